// Round 6
// baseline (13.067 us; speedup 1.0000x reference)
//
#include <hip/hip_runtime.h>

#define B_ 8
#define C_ 64
#define N_ 4096
#define K_ 16
#define THREADS 512
#define CG 8                 // channels per block (one packed-bf16 uint4/node)
#define NQ 8                 // node eighths -> grid = 8 * 8 * 8 = 512, 2 blocks/CU
#define NPB (N_ / NQ)        // 512 nodes gathered per block

// bf16 round-half-up pack: lo -> bits[15:0], hi -> bits[31:16].
__device__ __forceinline__ unsigned pack2(float lo, float hi) {
  return ((__float_as_uint(lo) + 0x8000u) >> 16) |
         ((__float_as_uint(hi) + 0x8000u) & 0xffff0000u);
}

// One block per (batch, channel-oct, node-eighth). 64 KB LDS -> two blocks
// co-resident per CU: one block's gather (DS pipe) overlaps the other's
// stage (VMEM pipe) instead of the whole CU idling at each phase.
__global__ __launch_bounds__(THREADS, 4) void fused_k(const float* __restrict__ x,
                                                      const int* __restrict__ ei,
                                                      const float* __restrict__ alpha_p,
                                                      float* __restrict__ out) {
  __shared__ uint4 xs[N_];            // 64 KB: all 4096 nodes x 8 ch, bf16-packed
  const int bid = blockIdx.x;         // 512 = 8 b * 8 cg * 8 nq
  const int b   = bid & 7;            // batch on low bits -> per-XCD x/ei locality
  const int cg  = (bid >> 3) & 7;
  const int nq  = bid >> 6;
  const int c0  = cg * CG;
  const int t   = threadIdx.x;

  const float* xb = x + ((size_t)b * C_ + c0) * N_;

  // Prefetch this thread's edge ids (L2 latency hides under staging).
  const int node = nq * NPB + t;
  const int4* ep = reinterpret_cast<const int4*>(ei + ((size_t)b * N_ + node) * K_);
  const int4 e0 = ep[0], e1 = ep[1], e2 = ep[2], e3 = ep[3];

  // Stage: 4 passes over node-pairs; 8 coalesced float2 row-loads (2 nodes x
  // 8 ch), bf16 pack, two ds_write_b128.
#pragma unroll
  for (int p = 0; p < N_ / (2 * THREADS); ++p) {
    const int j = p * THREADS + t;    // node-pair index
    const float2 r0 = *reinterpret_cast<const float2*>(xb + 0 * N_ + 2 * j);
    const float2 r1 = *reinterpret_cast<const float2*>(xb + 1 * N_ + 2 * j);
    const float2 r2 = *reinterpret_cast<const float2*>(xb + 2 * N_ + 2 * j);
    const float2 r3 = *reinterpret_cast<const float2*>(xb + 3 * N_ + 2 * j);
    const float2 r4 = *reinterpret_cast<const float2*>(xb + 4 * N_ + 2 * j);
    const float2 r5 = *reinterpret_cast<const float2*>(xb + 5 * N_ + 2 * j);
    const float2 r6 = *reinterpret_cast<const float2*>(xb + 6 * N_ + 2 * j);
    const float2 r7 = *reinterpret_cast<const float2*>(xb + 7 * N_ + 2 * j);
    uint4 w0, w1;
    w0.x = pack2(r0.x, r1.x); w0.y = pack2(r2.x, r3.x);
    w0.z = pack2(r4.x, r5.x); w0.w = pack2(r6.x, r7.x);
    w1.x = pack2(r0.y, r1.y); w1.y = pack2(r2.y, r3.y);
    w1.z = pack2(r4.y, r5.y); w1.w = pack2(r6.y, r7.y);
    xs[2 * j + 0] = w0;
    xs[2 * j + 1] = w1;
  }
  __syncthreads();

  int idx[K_];
  *reinterpret_cast<int4*>(&idx[0])  = e0;
  *reinterpret_cast<int4*>(&idx[4])  = e1;
  *reinterpret_cast<int4*>(&idx[8])  = e2;
  *reinterpret_cast<int4*>(&idx[12]) = e3;

  float acc[CG] = {0.f, 0.f, 0.f, 0.f, 0.f, 0.f, 0.f, 0.f};
#pragma unroll
  for (int k = 0; k < K_; ++k) {
    const uint4 v = xs[idx[k]];       // ds_read_b128: 8 channels, one edge
    acc[0] += __uint_as_float(v.x << 16);
    acc[1] += __uint_as_float(v.x & 0xffff0000u);
    acc[2] += __uint_as_float(v.y << 16);
    acc[3] += __uint_as_float(v.y & 0xffff0000u);
    acc[4] += __uint_as_float(v.z << 16);
    acc[5] += __uint_as_float(v.z & 0xffff0000u);
    acc[6] += __uint_as_float(v.w << 16);
    acc[7] += __uint_as_float(v.w & 0xffff0000u);
  }

  // Self term from LDS (bf16; error ~0.02 on 2x term, headroom 0.45).
  const uint4 sv = xs[node];          // lane-consecutive -> conflict-free
  float self[CG];
  self[0] = __uint_as_float(sv.x << 16);
  self[1] = __uint_as_float(sv.x & 0xffff0000u);
  self[2] = __uint_as_float(sv.y << 16);
  self[3] = __uint_as_float(sv.y & 0xffff0000u);
  self[4] = __uint_as_float(sv.z << 16);
  self[5] = __uint_as_float(sv.z & 0xffff0000u);
  self[6] = __uint_as_float(sv.w << 16);
  self[7] = __uint_as_float(sv.w & 0xffff0000u);

  const float s = 1.0f + alpha_p[0];
  float* ob = out + ((size_t)b * C_ + c0) * N_;
#pragma unroll
  for (int c = 0; c < CG; ++c) {
    ob[c * N_ + node] = self[c] * s + acc[c];   // coalesced dword rows
  }
}

extern "C" void kernel_launch(void* const* d_in, const int* in_sizes, int n_in,
                              void* d_out, int out_size, void* d_ws, size_t ws_size,
                              hipStream_t stream) {
  const float* x     = (const float*)d_in[0];
  const int*   ei    = (const int*)d_in[1];
  const float* alpha = (const float*)d_in[2];
  float*       out   = (float*)d_out;
  (void)d_ws; (void)ws_size;

  fused_k<<<B_ * (C_ / CG) * NQ, THREADS, 0, stream>>>(x, ei, alpha, out);
}

// Round 7
// 11.086 us; speedup vs baseline: 1.1787x; 1.1787x over previous
//
#include <hip/hip_runtime.h>

#define B_ 8
#define C_ 64
#define N_ 4096
#define K_ 16
#define THREADS 1024
#define CG 8                 // channels per block (one packed-f16 uint4/node)
#define NQ 4                 // node quarters -> grid = 8 * 8 * 4 = 256, 1 blk/CU

typedef __fp16 half2_t __attribute__((ext_vector_type(2)));

__device__ __forceinline__ unsigned pkrtz(float lo, float hi) {
  half2_t h = __builtin_amdgcn_cvt_pkrtz(lo, hi);   // v_cvt_pkrtz_f16_f32
  unsigned u; __builtin_memcpy(&u, &h, 4);
  return u;
}
__device__ __forceinline__ half2_t as_h2(unsigned u) {
  half2_t h; __builtin_memcpy(&h, &u, 4);
  return h;
}

// One block per (batch, channel-oct, node-quarter).
// All 4096 nodes x 8 channels staged in LDS as packed f16 (uint4/node, 64 KB).
// Gather = ONE ds_read_b128 per edge + 4x v_pk_add_f16 (no unpack VALU).
// Self term read fp32 from global (L1-hot from staging) -> exact dominant term.
__global__ __launch_bounds__(THREADS) void fused_k(const float* __restrict__ x,
                                                   const int* __restrict__ ei,
                                                   const float* __restrict__ alpha_p,
                                                   float* __restrict__ out) {
  __shared__ uint4 xs[N_];            // 64 KB
  const int bid = blockIdx.x;         // 256 = 8 b * 8 cg * 4 nq
  const int b   = bid & 7;            // batch on low bits -> per-XCD x/ei locality
  const int cg  = (bid >> 3) & 7;
  const int nq  = bid >> 6;
  const int c0  = cg * CG;
  const int t   = threadIdx.x;

  const float* xb = x + ((size_t)b * C_ + c0) * N_;

  // Prefetch this thread's edge ids (hides L2 latency under staging).
  const int node = nq * (N_ / NQ) + t;
  const int4* ep = reinterpret_cast<const int4*>(ei + ((size_t)b * N_ + node) * K_);
  const int4 e0 = ep[0], e1 = ep[1], e2 = ep[2], e3 = ep[3];

  // Stage: 4 passes; per pass 8 coalesced dword row-loads (lane = node),
  // pack via cvt_pkrtz, ONE lane-consecutive ds_write_b128 (conflict-free).
#pragma unroll
  for (int p = 0; p < N_ / THREADS; ++p) {
    const int n = p * THREADS + t;
    float r[CG];
#pragma unroll
    for (int c = 0; c < CG; ++c) r[c] = xb[c * N_ + n];
    uint4 w;
    w.x = pkrtz(r[0], r[1]);
    w.y = pkrtz(r[2], r[3]);
    w.z = pkrtz(r[4], r[5]);
    w.w = pkrtz(r[6], r[7]);
    xs[n] = w;
  }
  __syncthreads();

  int idx[K_];
  *reinterpret_cast<int4*>(&idx[0])  = e0;
  *reinterpret_cast<int4*>(&idx[4])  = e1;
  *reinterpret_cast<int4*>(&idx[8])  = e2;
  *reinterpret_cast<int4*>(&idx[12]) = e3;

  half2_t a0 = {0, 0}, a1 = {0, 0}, a2 = {0, 0}, a3 = {0, 0};
#pragma unroll
  for (int k = 0; k < K_; ++k) {
    const uint4 v = xs[idx[k]];       // ds_read_b128: 8 channels, one edge
    a0 += as_h2(v.x);                 // v_pk_add_f16
    a1 += as_h2(v.y);
    a2 += as_h2(v.z);
    a3 += as_h2(v.w);
  }

  float acc[CG];
  acc[0] = (float)a0[0]; acc[1] = (float)a0[1];
  acc[2] = (float)a1[0]; acc[3] = (float)a1[1];
  acc[4] = (float)a2[0]; acc[5] = (float)a2[1];
  acc[6] = (float)a3[0]; acc[7] = (float)a3[1];

  const float s = 1.0f + alpha_p[0];
  float* ob = out + ((size_t)b * C_ + c0) * N_;
#pragma unroll
  for (int c = 0; c < CG; ++c) {
    ob[c * N_ + node] = xb[c * N_ + node] * s + acc[c];  // self fp32-exact
  }
}

extern "C" void kernel_launch(void* const* d_in, const int* in_sizes, int n_in,
                              void* d_out, int out_size, void* d_ws, size_t ws_size,
                              hipStream_t stream) {
  const float* x     = (const float*)d_in[0];
  const int*   ei    = (const int*)d_in[1];
  const float* alpha = (const float*)d_in[2];
  float*       out   = (float*)d_out;
  (void)d_ws; (void)ws_size;

  fused_k<<<B_ * (C_ / CG) * NQ, THREADS, 0, stream>>>(x, ei, alpha, out);
}

// Round 8
// 11.051 us; speedup vs baseline: 1.1824x; 1.0032x over previous
//
#include <hip/hip_runtime.h>

#define B_ 8
#define C_ 64
#define N_ 4096
#define K_ 16
#define THREADS 1024
#define NQ 4                 // node quarters -> grid = 8 b * 8 cg * 4 nq = 256

typedef __fp16 half2_t __attribute__((ext_vector_type(2)));

__device__ __forceinline__ unsigned pkrtz(float lo, float hi) {
  half2_t h = __builtin_amdgcn_cvt_pkrtz(lo, hi);   // v_cvt_pkrtz_f16_f32
  unsigned u; __builtin_memcpy(&u, &h, 4);
  return u;
}
__device__ __forceinline__ half2_t as_h2(unsigned u) {
  half2_t h; __builtin_memcpy(&h, &u, 4);
  return h;
}

// One block per (batch, channel-oct, node-quarter); channels split A/B into
// two 32 KB f16 LDS buffers so phase-B staging overlaps phase-A gather:
//   stage A | barrier | issue B loads ; gather A ; out A ; pack+write B |
//   barrier | gather B ; out B
__global__ __launch_bounds__(THREADS) void fused_k(const float* __restrict__ x,
                                                   const int* __restrict__ ei,
                                                   const float* __restrict__ alpha_p,
                                                   float* __restrict__ out) {
  __shared__ uint2 xsA[N_];           // 32 KB: ch c0..c0+3, all 4096 nodes
  __shared__ uint2 xsB[N_];           // 32 KB: ch c0+4..c0+7
  const int bid = blockIdx.x;
  const int b   = bid & 7;            // batch on low bits -> per-XCD x/ei locality
  const int cg  = (bid >> 3) & 7;
  const int nq  = bid >> 6;
  const int c0  = cg * 8;
  const int t   = threadIdx.x;

  const float* xbA = x + ((size_t)b * C_ + c0) * N_;
  const float* xbB = xbA + 4 * N_;

  // Edge-id prefetch (hides L2 latency under stage A).
  const int node = nq * (N_ / NQ) + t;
  const int4* ep = reinterpret_cast<const int4*>(ei + ((size_t)b * N_ + node) * K_);
  const int4 e0 = ep[0], e1 = ep[1], e2 = ep[2], e3 = ep[3];

  // ---- stage A: 4 passes, 4 coalesced dword row-loads + 1 ds_write_b64 ----
#pragma unroll
  for (int p = 0; p < N_ / THREADS; ++p) {
    const int n = p * THREADS + t;
    const float r0 = xbA[0 * N_ + n], r1 = xbA[1 * N_ + n];
    const float r2 = xbA[2 * N_ + n], r3 = xbA[3 * N_ + n];
    uint2 w; w.x = pkrtz(r0, r1); w.y = pkrtz(r2, r3);
    xsA[n] = w;
  }
  __syncthreads();

  int idx[K_];
  *reinterpret_cast<int4*>(&idx[0])  = e0;
  *reinterpret_cast<int4*>(&idx[4])  = e1;
  *reinterpret_cast<int4*>(&idx[8])  = e2;
  *reinterpret_cast<int4*>(&idx[12]) = e3;

  // ---- issue B's global loads NOW; they retire under gather A ----
  float rb[N_ / THREADS][4];
#pragma unroll
  for (int p = 0; p < N_ / THREADS; ++p) {
    const int n = p * THREADS + t;
#pragma unroll
    for (int c = 0; c < 4; ++c) rb[p][c] = xbB[c * N_ + n];
  }

  // ---- gather A (32 random ds_read_b64 ... 16 edges x uint2) ----
  half2_t a0 = {0, 0}, a1 = {0, 0};
#pragma unroll
  for (int k = 0; k < K_; ++k) {
    const uint2 v = xsA[idx[k]];
    a0 += as_h2(v.x);                 // v_pk_add_f16
    a1 += as_h2(v.y);
  }
  const uint2 svA = xsA[node];        // self term (lane-consecutive, clean)

  const float s = 1.0f + alpha_p[0];
  float* obA = out + ((size_t)b * C_ + c0) * N_;
  {
    const half2_t s0 = as_h2(svA.x), s1 = as_h2(svA.y);
    obA[0 * N_ + node] = (float)s0[0] * s + (float)a0[0];
    obA[1 * N_ + node] = (float)s0[1] * s + (float)a0[1];
    obA[2 * N_ + node] = (float)s1[0] * s + (float)a1[0];
    obA[3 * N_ + node] = (float)s1[1] * s + (float)a1[1];
  }

  // ---- pack + write B (loads already in flight since before gather A) ----
#pragma unroll
  for (int p = 0; p < N_ / THREADS; ++p) {
    const int n = p * THREADS + t;
    uint2 w; w.x = pkrtz(rb[p][0], rb[p][1]); w.y = pkrtz(rb[p][2], rb[p][3]);
    xsB[n] = w;
  }
  __syncthreads();

  // ---- gather B + out B ----
  half2_t b0 = {0, 0}, b1 = {0, 0};
#pragma unroll
  for (int k = 0; k < K_; ++k) {
    const uint2 v = xsB[idx[k]];
    b0 += as_h2(v.x);
    b1 += as_h2(v.y);
  }
  const uint2 svB = xsB[node];
  float* obB = obA + 4 * N_;
  {
    const half2_t s0 = as_h2(svB.x), s1 = as_h2(svB.y);
    obB[0 * N_ + node] = (float)s0[0] * s + (float)b0[0];
    obB[1 * N_ + node] = (float)s0[1] * s + (float)b0[1];
    obB[2 * N_ + node] = (float)s1[0] * s + (float)b1[0];
    obB[3 * N_ + node] = (float)s1[1] * s + (float)b1[1];
  }
}

extern "C" void kernel_launch(void* const* d_in, const int* in_sizes, int n_in,
                              void* d_out, int out_size, void* d_ws, size_t ws_size,
                              hipStream_t stream) {
  const float* x     = (const float*)d_in[0];
  const int*   ei    = (const int*)d_in[1];
  const float* alpha = (const float*)d_in[2];
  float*       out   = (float*)d_out;
  (void)d_ws; (void)ws_size;

  fused_k<<<B_ * 8 * NQ, THREADS, 0, stream>>>(x, ei, alpha, out);
}